// Round 9
// baseline (1005.060 us; speedup 1.0000x reference)
//
#include <hip/hip_runtime.h>
#include <hip/hip_bf16.h>

#define D_MODEL 768
#define N_HEADS 12
#define D_HEAD  64
#define D_FF    3072
#define N_LAYERS 4
#define VOCAB   32000
#define BATCH   4
#define SEQ     1024
#define NROWS   (BATCH*SEQ)      // 4096
#define NEGV    -1000000000.0f
#define LN_EPS  1e-5f

typedef __attribute__((ext_vector_type(8))) short bf16x8;
typedef __attribute__((ext_vector_type(4))) float f32x4;
typedef __attribute__((ext_vector_type(8))) unsigned short u16x8;
typedef __attribute__((ext_vector_type(4))) unsigned short u16x4;

typedef __attribute__((address_space(1))) const unsigned int g_u32;
typedef __attribute__((address_space(3))) unsigned int l_u32;

__device__ __forceinline__ float bf2f(unsigned short u) {
  return __uint_as_float(((unsigned int)u) << 16);
}
__device__ __forceinline__ unsigned short f2bf(float f) {
  __hip_bfloat16 h = __float2bfloat16(f);
  return *reinterpret_cast<unsigned short*>(&h);
}

__device__ __forceinline__ float block_reduce_sum(float v, float* sbuf) {
#pragma unroll
  for (int off = 32; off > 0; off >>= 1) v += __shfl_down(v, off, 64);
  int lane = threadIdx.x & 63, wid = threadIdx.x >> 6;
  if (lane == 0) sbuf[wid] = v;
  __syncthreads();
  if (threadIdx.x == 0) sbuf[4] = sbuf[0] + sbuf[1] + sbuf[2] + sbuf[3];
  __syncthreads();
  return sbuf[4];
}

// gelu via exact identity 0.5*(1+tanh(z)) == sigmoid(2z):
// one v_exp_f32 instead of libm tanhf (~10x cheaper epilogue).
__device__ __forceinline__ float gelu_f(float x) {
  float z2 = 1.5957691216f * x * (1.0f + 0.044715f * x * x);  // 2*0.79788456*(x+0.044715x^3)
  return x / (1.0f + __expf(-z2));
}

// pack wq|wk|wv of all layers into wqkvb [l][3*WMAT] in one launch
__global__ __launch_bounds__(256) void qkv_pack_kernel(
    const float* __restrict__ wq, const float* __restrict__ wk,
    const float* __restrict__ wv, __hip_bfloat16* __restrict__ dst)
{
  const int WMAT = D_MODEL * D_MODEL;
  long long i = (long long)(blockIdx.x * 256 + threadIdx.x) * 8;
  long long l = i / (3LL * WMAT);
  long long rem = i - l * 3LL * WMAT;
  int which = (int)(rem / WMAT);
  long long off = rem - (long long)which * WMAT;
  const float* src = (which == 0 ? wq : which == 1 ? wk : wv) + l * WMAT + off;
  float4 a = *(const float4*)src;
  float4 b = *(const float4*)(src + 4);
  struct bf8 { __hip_bfloat16 h[8]; } r;
  r.h[0] = __float2bfloat16(a.x); r.h[1] = __float2bfloat16(a.y);
  r.h[2] = __float2bfloat16(a.z); r.h[3] = __float2bfloat16(a.w);
  r.h[4] = __float2bfloat16(b.x); r.h[5] = __float2bfloat16(b.y);
  r.h[6] = __float2bfloat16(b.z); r.h[7] = __float2bfloat16(b.w);
  *(bf8*)(dst + i) = r;
}

// convert wo|fc1|fc2 (all layers) into contiguous wob|fc1b|fc2b in one launch
__global__ __launch_bounds__(256) void convert3_kernel(
    const float* __restrict__ wo, const float* __restrict__ fc1,
    const float* __restrict__ fc2, __hip_bfloat16* __restrict__ dst)
{
  const long long WM4 = 4LL * D_MODEL * D_MODEL;   // 2,359,296
  const long long FM4 = 4LL * D_FF * D_MODEL;      // 9,437,184
  long long i = (long long)(blockIdx.x * 256 + threadIdx.x) * 8;
  const float* src;
  if (i < WM4)            src = wo  + i;
  else if (i < WM4 + FM4) src = fc1 + (i - WM4);
  else                    src = fc2 + (i - WM4 - FM4);
  float4 a = *(const float4*)src;
  float4 b = *(const float4*)(src + 4);
  struct bf8 { __hip_bfloat16 h[8]; } r;
  r.h[0] = __float2bfloat16(a.x); r.h[1] = __float2bfloat16(a.y);
  r.h[2] = __float2bfloat16(a.z); r.h[3] = __float2bfloat16(a.w);
  r.h[4] = __float2bfloat16(b.x); r.h[5] = __float2bfloat16(b.y);
  r.h[6] = __float2bfloat16(b.z); r.h[7] = __float2bfloat16(b.w);
  *(bf8*)(dst + i) = r;
}

// ---------- embedding transpose: emb [768][32000] f32 -> embT [32000][768] bf16 ----------
__global__ __launch_bounds__(256) void transpose_emb_kernel(
    const float* __restrict__ emb, __hip_bfloat16* __restrict__ embT)
{
  __shared__ float tile[64][65];
  const int vb = blockIdx.x * 64;   // vocab block
  const int db = blockIdx.y * 64;   // d block
  const int tid = threadIdx.x;
  {
    int r = tid >> 4, c = (tid & 15) * 4;
#pragma unroll
    for (int p = 0; p < 4; ++p) {
      float4 v = *(const float4*)(emb + (size_t)(db + r + p * 16) * VOCAB + vb + c);
      tile[c + 0][r + p * 16] = v.x;
      tile[c + 1][r + p * 16] = v.y;
      tile[c + 2][r + p * 16] = v.z;
      tile[c + 3][r + p * 16] = v.w;
    }
  }
  __syncthreads();
  {
    int v = tid >> 2, d0 = (tid & 3) * 16;
    unsigned short* op = (unsigned short*)embT + (size_t)(vb + v) * D_MODEL + db + d0;
    u16x8 o0, o1;
#pragma unroll
    for (int j = 0; j < 8; ++j) {
      o0[j] = f2bf(tile[v][d0 + j]);
      o1[j] = f2bf(tile[v][d0 + 8 + j]);
    }
    *(u16x8*)op = o0;
    *(u16x8*)(op + 8) = o1;
  }
}

// ---------- embedding gather (coalesced) + positional encoding ----------
__global__ __launch_bounds__(256) void embed_kernel(
    const int* __restrict__ tokens, const __hip_bfloat16* __restrict__ embT,
    float* __restrict__ x)
{
  int bs = blockIdx.x;
  int s = bs & (SEQ - 1);
  int tok = tokens[bs];
  const unsigned short* ep = (const unsigned short*)embT + (size_t)tok * D_MODEL;
  for (int d = threadIdx.x; d < D_MODEL; d += 256) {
    float ev = bf2f(ep[d]);
    int dpair = d & ~1;
    float expo = (float)dpair * (1.0f / (float)D_MODEL);
    float ang = (float)s / powf(10000.0f, expo);
    float pe = (d & 1) ? cosf(ang) : sinf(ang);
    x[(size_t)bs * D_MODEL + d] = ev + pe;
  }
}

// ---------- layer norm (fp32 in, bf16 out) ----------
__global__ __launch_bounds__(256) void ln_kernel(
    const float* __restrict__ in, __hip_bfloat16* __restrict__ out,
    const float* __restrict__ g, const float* __restrict__ bb)
{
  __shared__ float sbuf[8];
  size_t row = blockIdx.x;
  const float* rp = in + row * D_MODEL;
  int t = threadIdx.x;
  float x0 = rp[t], x1 = rp[t + 256], x2 = rp[t + 512];
  float mean = block_reduce_sum(x0 + x1 + x2, sbuf) * (1.0f / (float)D_MODEL);
  float d0 = x0 - mean, d1 = x1 - mean, d2 = x2 - mean;
  float var = block_reduce_sum(d0*d0 + d1*d1 + d2*d2, sbuf) * (1.0f / (float)D_MODEL);
  float rstd = rsqrtf(var + LN_EPS);
  __hip_bfloat16* op = out + row * D_MODEL;
  op[t]       = __float2bfloat16(g[t]       * (d0 * rstd) + bb[t]);
  op[t + 256] = __float2bfloat16(g[t + 256] * (d1 * rstd) + bb[t + 256]);
  op[t + 512] = __float2bfloat16(g[t + 512] * (d2 * rstd) + bb[t + 512]);
}

// final LN on x[b, predict_idx, :] (fp32 out)
__global__ __launch_bounds__(256) void final_ln_kernel(
    const float* __restrict__ x, const int* __restrict__ pidx,
    const float* __restrict__ g, const float* __restrict__ bb,
    float* __restrict__ out)
{
  __shared__ float sbuf[8];
  int p = pidx[0];
  const float* rp = x + ((size_t)blockIdx.x * SEQ + p) * D_MODEL;
  int t = threadIdx.x;
  float x0 = rp[t], x1 = rp[t + 256], x2 = rp[t + 512];
  float mean = block_reduce_sum(x0 + x1 + x2, sbuf) * (1.0f / (float)D_MODEL);
  float d0 = x0 - mean, d1 = x1 - mean, d2 = x2 - mean;
  float var = block_reduce_sum(d0*d0 + d1*d1 + d2*d2, sbuf) * (1.0f / (float)D_MODEL);
  float rstd = rsqrtf(var + LN_EPS);
  float* op = out + (size_t)blockIdx.x * D_MODEL;
  op[t]       = g[t]       * (d0 * rstd) + bb[t];
  op[t + 256] = g[t + 256] * (d1 * rstd) + bb[t + 256];
  op[t + 512] = g[t + 512] * (d2 * rstd) + bb[t + 512];
}

// XCD-chunked bijective block swizzle (nwg % 8 == 0 for all our grids)
__device__ __forceinline__ int2 xcd_tile(int gx, int gy) {
  int flat = blockIdx.y * gx + blockIdx.x;
  int cpx = (gx * gy) >> 3;
  int logical = (flat & 7) * cpx + (flat >> 3);
  return make_int2(logical % gx, logical / gx);   // (col, row)
}

#define WAITV4() asm volatile("s_waitcnt vmcnt(4)" ::: "memory")
#define WAITV0() asm volatile("s_waitcnt vmcnt(0)" ::: "memory")
#define MEMFENCE() asm volatile("" ::: "memory")

// ---------- bf16 MFMA NT GEMM, ring-3 counted-vmcnt pipeline ----------
// 128x128 tile, BK=32, 3 LDS buffers, depth-2 prefetch (proven round 6).
// Now also used for N=768 GEMMs (wo, fc2): 192 blocks, 3/CU resident.
__global__ __launch_bounds__(256) void gemm_bf16_kernel(
    const __hip_bfloat16* __restrict__ A, const __hip_bfloat16* __restrict__ W,
    void* __restrict__ Cv, const float* __restrict__ resid,
    int N, int K, int mode)
{
  __shared__ __align__(16) unsigned short As[3][128 * 32];   // 24 KB
  __shared__ __align__(16) unsigned short Bs[3][128 * 32];   // 24 KB
  const unsigned short* Au = (const unsigned short*)A;
  const unsigned short* Wu = (const unsigned short*)W;
  const int tid = threadIdx.x;
  const int wv = tid >> 6, ln = tid & 63;
  const int l15 = ln & 15, l4 = ln >> 4;
  int2 tc = xcd_tile(N >> 7, gridDim.y);
  const int bm = tc.y * 128, bn = tc.x * 128;
  const int wr = wv >> 1, wc = wv & 1;

  const int lrow = wv * 16 + (ln >> 2);
  const int schunk = (ln & 3) ^ ((ln >> 3) & 3);
  const size_t gA0 = (size_t)(bm + lrow) * K + schunk * 8;
  const size_t gA1 = (size_t)(bm + 64 + lrow) * K + schunk * 8;
  const size_t gB0 = (size_t)(bn + lrow) * K + schunk * 8;
  const size_t gB1 = (size_t)(bn + 64 + lrow) * K + schunk * 8;
  const int ldsb = wv * 512;

#define STAGE128(buf, k0)                                                          \
  {                                                                                \
    __builtin_amdgcn_global_load_lds((g_u32*)(Au + gA0 + (k0)), (l_u32*)(As[buf] + ldsb), 16, 0, 0);        \
    __builtin_amdgcn_global_load_lds((g_u32*)(Au + gA1 + (k0)), (l_u32*)(As[buf] + 2048 + ldsb), 16, 0, 0); \
    __builtin_amdgcn_global_load_lds((g_u32*)(Wu + gB0 + (k0)), (l_u32*)(Bs[buf] + ldsb), 16, 0, 0);        \
    __builtin_amdgcn_global_load_lds((g_u32*)(Wu + gB1 + (k0)), (l_u32*)(Bs[buf] + 2048 + ldsb), 16, 0, 0); \
  }

  const int rslot = (l4 ^ ((l15 >> 1) & 3)) * 8;

#define COMPUTE128(buf)                                                            \
  {                                                                                \
    bf16x8 af[4], bfr[4];                                                          \
    _Pragma("unroll")                                                              \
    for (int m = 0; m < 4; ++m)                                                    \
      af[m] = *(const bf16x8*)(As[buf] + (wr * 64 + m * 16 + l15) * 32 + rslot);   \
    _Pragma("unroll")                                                              \
    for (int n = 0; n < 4; ++n)                                                    \
      bfr[n] = *(const bf16x8*)(Bs[buf] + (wc * 64 + n * 16 + l15) * 32 + rslot);  \
    __builtin_amdgcn_s_setprio(1);                                                 \
    _Pragma("unroll")                                                              \
    for (int m = 0; m < 4; ++m)                                                    \
      _Pragma("unroll")                                                            \
      for (int n = 0; n < 4; ++n)                                                  \
        acc[m][n] = __builtin_amdgcn_mfma_f32_16x16x32_bf16(af[m], bfr[n], acc[m][n], 0, 0, 0); \
    __builtin_amdgcn_s_setprio(0);                                                 \
  }

  f32x4 acc[4][4];
#pragma unroll
  for (int m = 0; m < 4; ++m)
#pragma unroll
    for (int n = 0; n < 4; ++n) acc[m][n] = (f32x4){0.f, 0.f, 0.f, 0.f};

  const int NT = K >> 5;
  STAGE128(0, 0);
  STAGE128(1, 32);
  int cur = 0;
  for (int t = 0; t < NT - 1; ++t) {
    WAITV4();
    __builtin_amdgcn_s_barrier();
    MEMFENCE();
    if (t + 2 < NT) {
      int nxt = cur + 2; if (nxt >= 3) nxt -= 3;
      STAGE128(nxt, (t + 2) << 5);
    }
    COMPUTE128(cur);
    cur = (cur == 2) ? 0 : cur + 1;
  }
  WAITV0();
  __builtin_amdgcn_s_barrier();
  MEMFENCE();
  COMPUTE128(cur);

  float* Cf = (float*)Cv;
  __hip_bfloat16* Cb = (__hip_bfloat16*)Cv;
#pragma unroll
  for (int m = 0; m < 4; ++m) {
#pragma unroll
    for (int n = 0; n < 4; ++n) {
#pragma unroll
      for (int r = 0; r < 4; ++r) {
        int row = bm + wr * 64 + m * 16 + l4 * 4 + r;
        int col = bn + wc * 64 + n * 16 + l15;
        size_t off = (size_t)row * N + col;
        float v = acc[m][n][r];
        if (mode == 0)      Cf[off] = v;
        else if (mode == 1) Cf[off] = v + resid[off];
        else if (mode == 2) Cb[off] = __float2bfloat16(v);
        else                Cb[off] = __float2bfloat16(gelu_f(v));
      }
    }
  }
#undef STAGE128
#undef COMPUTE128
}

// ---------- MFMA flash attention v2 (proven round 7) ----------
__global__ __launch_bounds__(128) void flash_attn_kernel(
    const __hip_bfloat16* __restrict__ qkv_, __hip_bfloat16* __restrict__ attn_)
{
  const unsigned short* qkv = (const unsigned short*)qkv_;
  unsigned short* attn = (unsigned short*)attn_;
  const int px = blockIdx.x;        // pair index 0..15
  const int h  = blockIdx.y;
  const int b  = blockIdx.z;
  const int tid = threadIdx.x;      // 0..127
  const int wq = tid >> 6, ln = tid & 63;
  const int l15 = ln & 15, l4 = ln >> 4;

  __shared__ unsigned short Ks[2][64 * 64];   // 16 KB, [t][d] XOR-swizzled
  __shared__ unsigned short Vt[2][64 * 64];   // 16 KB, [e][t] XOR-swizzled
  __shared__ unsigned short Pw[2][16 * 64];   // 4 KB, per-wave P [q][t]

  const int krow = tid >> 3;
  const int kchunk = (tid & 7) ^ ((tid >> 3) & 7);
  const int kldsbase = (tid & 64) * 8;   // wave-uniform base (elems)

  const int vc = tid & 7;          // e-chunk
  const int vp = tid >> 3;         // 0..15
  const int vtr = (2 * vp) & 7;    // even within-chunk t offset
  const int vtb0 = vp >> 2;        // t-chunk of rows 2vp..

  u16x8 v0, v1, v2, v3;            // V prefetch registers

#define STAGE_K(buf, t0)                                                           \
  {                                                                                \
    _Pragma("unroll")                                                              \
    for (int j = 0; j < 4; ++j) {                                                  \
      const unsigned short* gk = qkv +                                             \
          (size_t)(b * SEQ + (t0) + j * 16 + krow) * 2304 + 768 + h * 64 + kchunk * 8; \
      __builtin_amdgcn_global_load_lds((g_u32*)gk,                                 \
          (l_u32*)(Ks[buf] + j * 1024 + kldsbase), 16, 0, 0);                      \
    }                                                                              \
  }

#define LOAD_V(t0)                                                                 \
  {                                                                                \
    const unsigned short* gv = qkv +                                               \
        (size_t)(b * SEQ + (t0) + 2 * vp) * 2304 + 1536 + h * 64 + vc * 8;         \
    v0 = *(const u16x8*)gv;                                                        \
    v1 = *(const u16x8*)(gv + 2304);                                               \
    v2 = *(const u16x8*)(gv + 32 * 2304);                                          \
    v3 = *(const u16x8*)(gv + 33 * 2304);                                          \
  }

#define WRITE_VT(buf)                                                              \
  {                                                                                \
    _Pragma("unroll")                                                              \
    for (int j = 0; j < 8; ++j) {                                                  \
      int e = vc * 8 + j;                                                          \
      unsigned int w01 = (unsigned int)(unsigned short)v0[j] |                     \
                         ((unsigned int)(unsigned short)v1[j] << 16);              \
      unsigned int w23 = (unsigned int)(unsigned short)v2[j] |                     \
                         ((unsigned int)(unsigned short)v3[j] << 16);              \
      *(unsigned int*)(Vt[buf] + e * 64 + ((vtb0 ^ (e & 7)) << 3) + vtr) = w01;    \
      *(unsigned int*)(Vt[buf] + e * 64 + (((vtb0 + 4) ^ (e & 7)) << 3) + vtr) = w23; \
    }                                                                              \
  }

  for (int pass = 0; pass < 2; ++pass) {
    const int qi = (pass == 0) ? px : 31 - px;
    const int s0 = qi * 32;
    const int ntiles = (qi >> 1) + 1;
    const int qg = s0 + wq * 16 + l15;   // this lane's q row

    bf16x8 qf[2];
    {
      const size_t qbase = (size_t)(b * SEQ + qg) * 2304 + h * 64;
#pragma unroll
      for (int ks = 0; ks < 2; ++ks) {
        u16x8 raw = *(const u16x8*)(qkv + qbase + ks * 32 + l4 * 8);
        bf16x8 q;
#pragma unroll
        for (int j = 0; j < 8; ++j) q[j] = (short)f2bf(bf2f(raw[j]) * 0.125f);
        qf[ks] = q;
      }
    }

    float mrow = -1e30f, lrow = 0.f;
    f32x4 o[4];
#pragma unroll
    for (int n = 0; n < 4; ++n) o[n] = (f32x4){0.f, 0.f, 0.f, 0.f};

    STAGE_K(0, 0);
    LOAD_V(0);
    WAITV0();
    WRITE_VT(0);
    __syncthreads();

    for (int t = 0; t < ntiles; ++t) {
      const int cur = t & 1;
      const bool pfn = (t + 1 < ntiles);
      if (pfn) { STAGE_K(cur ^ 1, (t + 1) * 64); LOAD_V((t + 1) * 64); }

      f32x4 sf[4];
#pragma unroll
      for (int n = 0; n < 4; ++n) sf[n] = (f32x4){0.f, 0.f, 0.f, 0.f};
#pragma unroll
      for (int ks = 0; ks < 2; ++ks) {
#pragma unroll
        for (int n = 0; n < 4; ++n) {
          int tr = n * 16 + l15;
          bf16x8 kf = *(const bf16x8*)(Ks[cur] + tr * 64 + (((ks * 4 + l4) ^ (tr & 7)) << 3));
          sf[n] = __builtin_amdgcn_mfma_f32_16x16x32_bf16(kf, qf[ks], sf[n], 0, 0, 0);
        }
      }

      if (t == ntiles - 1) {
#pragma unroll
        for (int n = 0; n < 4; ++n) {
#pragma unroll
          for (int r = 0; r < 4; ++r) {
            int tg = t * 64 + n * 16 + l4 * 4 + r;
            if (tg > qg) sf[n][r] = NEGV;
          }
        }
      }

      float mx = sf[0][0];
#pragma unroll
      for (int n = 0; n < 4; ++n)
#pragma unroll
        for (int r = 0; r < 4; ++r) mx = fmaxf(mx, sf[n][r]);
      mx = fmaxf(mx, __shfl_xor(mx, 16));
      mx = fmaxf(mx, __shfl_xor(mx, 32));
      float mnew = fmaxf(mrow, mx);
      float alpha = __expf(mrow - mnew);
      float pb[4][4];
      float sum = 0.f;
#pragma unroll
      for (int n = 0; n < 4; ++n)
#pragma unroll
        for (int r = 0; r < 4; ++r) {
          float p = __expf(sf[n][r] - mnew);
          pb[n][r] = p;
          sum += p;
        }
      sum += __shfl_xor(sum, 16);
      sum += __shfl_xor(sum, 32);
      lrow = lrow * alpha + sum;
      mrow = mnew;

      float ar[4];
#pragma unroll
      for (int r = 0; r < 4; ++r)
        ar[r] = __shfl(alpha, (ln & 48) | (l4 * 4 + r));
#pragma unroll
      for (int n = 0; n < 4; ++n)
#pragma unroll
        for (int r = 0; r < 4; ++r) o[n][r] *= ar[r];

      unsigned short* Pme = Pw[wq];
#pragma unroll
      for (int n = 0; n < 4; ++n) {
        int tb = 2 * n + (l4 >> 1);
        u16x4 w;
        w[0] = f2bf(pb[n][0]); w[1] = f2bf(pb[n][1]);
        w[2] = f2bf(pb[n][2]); w[3] = f2bf(pb[n][3]);
        *(u16x4*)(Pme + l15 * 64 + ((tb ^ (l15 & 7)) << 3) + (l4 & 1) * 4) = w;
      }

#pragma unroll
      for (int ks = 0; ks < 2; ++ks) {
        bf16x8 pf = *(const bf16x8*)(Pme + l15 * 64 + (((ks * 4 + l4) ^ (l15 & 7)) << 3));
#pragma unroll
        for (int n = 0; n < 4; ++n) {
          int e = n * 16 + l15;
          bf16x8 vf = *(const bf16x8*)(Vt[cur] + e * 64 + (((ks * 4 + l4) ^ (e & 7)) << 3));
          o[n] = __builtin_amdgcn_mfma_f32_16x16x32_bf16(pf, vf, o[n], 0, 0, 0);
        }
      }

      if (pfn) { WAITV0(); WRITE_VT(cur ^ 1); }
      __syncthreads();
    }

    float lr[4];
#pragma unroll
    for (int r = 0; r < 4; ++r)
      lr[r] = __shfl(lrow, (ln & 48) | (l4 * 4 + r));
#pragma unroll
    for (int r = 0; r < 4; ++r) {
      float inv = 1.0f / lr[r];
      size_t base = (size_t)(b * SEQ + s0 + wq * 16 + l4 * 4 + r) * D_MODEL + h * 64;
#pragma unroll
      for (int n = 0; n < 4; ++n)
        attn[base + n * 16 + l15] = f2bf(o[n][r] * inv);
    }
  }
#undef STAGE_K
#undef LOAD_V
#undef WRITE_VT
}

// ---------- logits: out[b,v] = dot(normed[b,:], unembed[v,:]) ----------
__global__ __launch_bounds__(256) void logits_kernel(
    const float* __restrict__ normed, const float* __restrict__ unemb,
    float* __restrict__ out)
{
  __shared__ __align__(16) float ns[BATCH][D_MODEL];
  for (int d = threadIdx.x; d < BATCH * D_MODEL; d += 256)
    ((float*)ns)[d] = normed[d];
  __syncthreads();
  int g = threadIdx.x >> 4, li = threadIdx.x & 15;
  int v = blockIdx.x * 16 + g;
  const float* up = unemb + (size_t)v * D_MODEL;
  float s0 = 0.f, s1 = 0.f, s2 = 0.f, s3 = 0.f;
#pragma unroll
  for (int it = 0; it < D_MODEL / 64; ++it) {
    int e = it * 64 + li * 4;
    float4 u = *(const float4*)(up + e);
    float4 n0 = *(const float4*)&ns[0][e];
    float4 n1 = *(const float4*)&ns[1][e];
    float4 n2 = *(const float4*)&ns[2][e];
    float4 n3 = *(const float4*)&ns[3][e];
    s0 += u.x*n0.x + u.y*n0.y + u.z*n0.z + u.w*n0.w;
    s1 += u.x*n1.x + u.y*n1.y + u.z*n1.z + u.w*n1.w;
    s2 += u.x*n2.x + u.y*n2.y + u.z*n2.z + u.w*n2.w;
    s3 += u.x*n3.x + u.y*n3.y + u.z*n3.z + u.w*n3.w;
  }
#pragma unroll
  for (int msk = 1; msk < 16; msk <<= 1) {
    s0 += __shfl_xor(s0, msk, 64); s1 += __shfl_xor(s1, msk, 64);
    s2 += __shfl_xor(s2, msk, 64); s3 += __shfl_xor(s3, msk, 64);
  }
  if (li == 0) {
    out[(size_t)0 * VOCAB + v] = s0;
    out[(size_t)1 * VOCAB + v] = s1;
    out[(size_t)2 * VOCAB + v] = s2;
    out[(size_t)3 * VOCAB + v] = s3;
  }
}

// ---------- launcher ----------
extern "C" void kernel_launch(void* const* d_in, const int* in_sizes, int n_in,
                              void* d_out, int out_size, void* d_ws, size_t ws_size,
                              hipStream_t stream) {
  const int*   tokens = (const int*)d_in[0];
  const int*   pidx   = (const int*)d_in[1];
  const float* emb    = (const float*)d_in[2];
  const float* ln1_g  = (const float*)d_in[3];
  const float* ln1_b  = (const float*)d_in[4];
  const float* wq     = (const float*)d_in[5];
  const float* wk     = (const float*)d_in[6];
  const float* wv     = (const float*)d_in[7];
  const float* wo     = (const float*)d_in[8];
  const float* ln2_g  = (const float*)d_in[9];
  const float* ln2_b  = (const float*)d_in[10];
  const float* fc1    = (const float*)d_in[11];
  const float* fc2    = (const float*)d_in[12];
  const float* lnf_g  = (const float*)d_in[13];
  const float* lnf_b  = (const float*)d_in[14];
  const float* unemb  = (const float*)d_in[15];
  float* out = (float*)d_out;

  char* wp = (char*)d_ws;
  const size_t NX = (size_t)NROWS * D_MODEL;        // 3,145,728
  float* x = (float*)wp;                  wp += NX * 4;
  float* normed = (float*)wp;             wp += BATCH * D_MODEL * 4;
  __hip_bfloat16* h    = (__hip_bfloat16*)wp; wp += NX * 2;
  __hip_bfloat16* attn = (__hip_bfloat16*)wp; wp += NX * 2;
  __hip_bfloat16* qkvb = (__hip_bfloat16*)wp; wp += (size_t)NROWS * 2304 * 2;
  __hip_bfloat16* ffn  = (__hip_bfloat16*)wp; wp += (size_t)NROWS * D_FF * 2;
  __hip_bfloat16* wqkvb = (__hip_bfloat16*)wp; wp += (size_t)N_LAYERS * 2304 * D_MODEL * 2;
  __hip_bfloat16* wob   = (__hip_bfloat16*)wp; wp += (size_t)N_LAYERS * D_MODEL * D_MODEL * 2;
  __hip_bfloat16* fc1b  = (__hip_bfloat16*)wp; wp += (size_t)N_LAYERS * D_FF * D_MODEL * 2;
  __hip_bfloat16* fc2b  = (__hip_bfloat16*)wp; wp += (size_t)N_LAYERS * D_MODEL * D_FF * 2;

  // embT [VOCAB][D_MODEL] bf16 (49.2 MB) aliased onto attn..ffn scratch
  __hip_bfloat16* embT = attn;

  const int WMAT = D_MODEL * D_MODEL;     // 589824
  const int FMAT = D_FF * D_MODEL;        // 2359296

  transpose_emb_kernel<<<dim3(VOCAB / 64, D_MODEL / 64), 256, 0, stream>>>(emb, embT);
  embed_kernel<<<NROWS, 256, 0, stream>>>(tokens, embT, x);

  qkv_pack_kernel<<<N_LAYERS * 3 * WMAT / 2048, 256, 0, stream>>>(wq, wk, wv, wqkvb);
  // wob|fc1b|fc2b are contiguous: one fused convert launch
  convert3_kernel<<<(N_LAYERS * (WMAT + 2 * FMAT)) / 2048, 256, 0, stream>>>(wo, fc1, fc2, wob);

  for (int l = 0; l < N_LAYERS; ++l) {
    const size_t qofs = (size_t)l * 3 * WMAT;
    const size_t wofs = (size_t)l * WMAT;
    const size_t fofs = (size_t)l * FMAT;

    ln_kernel<<<NROWS, 256, 0, stream>>>(x, h, ln1_g + l * D_MODEL, ln1_b + l * D_MODEL);

    // fused QKV: [4096 x 2304] bf16 out
    gemm_bf16_kernel<<<dim3(2304 / 128, NROWS / 128), 256, 0, stream>>>(
        h, wqkvb + qofs, qkvb, nullptr, 2304, D_MODEL, 2);

    flash_attn_kernel<<<dim3(16, N_HEADS, BATCH), 128, 0, stream>>>(qkvb, attn);

    // x += attn @ wo^T  (128-tile ring-3: 192 blocks, 3/CU)
    gemm_bf16_kernel<<<dim3(D_MODEL / 128, NROWS / 128), 256, 0, stream>>>(
        attn, wob + wofs, x, x, D_MODEL, D_MODEL, 1);

    ln_kernel<<<NROWS, 256, 0, stream>>>(x, h, ln2_g + l * D_MODEL, ln2_b + l * D_MODEL);

    // ffn = gelu(h @ fc1^T) (bf16)
    gemm_bf16_kernel<<<dim3(D_FF / 128, NROWS / 128), 256, 0, stream>>>(
        h, fc1b + fofs, ffn, nullptr, D_FF, D_MODEL, 3);

    // x += ffn @ fc2^T  (128-tile ring-3: 192 blocks, K=3072 deep pipeline)
    gemm_bf16_kernel<<<dim3(D_MODEL / 128, NROWS / 128), 256, 0, stream>>>(
        ffn, fc2b + fofs, x, x, D_MODEL, D_FF, 1);
  }

  final_ln_kernel<<<BATCH, 256, 0, stream>>>(x, pidx, lnf_g, lnf_b, normed);
  logits_kernel<<<VOCAB / 16, 256, 0, stream>>>(normed, unemb, out);
}

// Round 10
// 785.528 us; speedup vs baseline: 1.2795x; 1.2795x over previous
//
#include <hip/hip_runtime.h>
#include <hip/hip_bf16.h>

#define D_MODEL 768
#define N_HEADS 12
#define D_HEAD  64
#define D_FF    3072
#define N_LAYERS 4
#define VOCAB   32000
#define BATCH   4
#define SEQ     1024
#define NROWS   (BATCH*SEQ)      // 4096
#define NEGV    -1000000000.0f
#define LN_EPS  1e-5f

typedef __attribute__((ext_vector_type(8))) short bf16x8;
typedef __attribute__((ext_vector_type(4))) float f32x4;
typedef __attribute__((ext_vector_type(8))) unsigned short u16x8;
typedef __attribute__((ext_vector_type(4))) unsigned short u16x4;

typedef __attribute__((address_space(1))) const unsigned int g_u32;
typedef __attribute__((address_space(3))) unsigned int l_u32;

__device__ __forceinline__ float bf2f(unsigned short u) {
  return __uint_as_float(((unsigned int)u) << 16);
}
__device__ __forceinline__ unsigned short f2bf(float f) {
  __hip_bfloat16 h = __float2bfloat16(f);
  return *reinterpret_cast<unsigned short*>(&h);
}

__device__ __forceinline__ float block_reduce_sum(float v, float* sbuf) {
#pragma unroll
  for (int off = 32; off > 0; off >>= 1) v += __shfl_down(v, off, 64);
  int lane = threadIdx.x & 63, wid = threadIdx.x >> 6;
  if (lane == 0) sbuf[wid] = v;
  __syncthreads();
  if (threadIdx.x == 0) sbuf[4] = sbuf[0] + sbuf[1] + sbuf[2] + sbuf[3];
  __syncthreads();
  return sbuf[4];
}

// gelu via exact identity 0.5*(1+tanh(z)) == sigmoid(2z):
// one v_exp_f32 instead of libm tanhf (~10x cheaper epilogue).
__device__ __forceinline__ float gelu_f(float x) {
  float z2 = 1.5957691216f * x * (1.0f + 0.044715f * x * x);
  return x / (1.0f + __expf(-z2));
}

// pack wq|wk|wv of all layers into wqkvb [l][3*WMAT] in one launch
__global__ __launch_bounds__(256) void qkv_pack_kernel(
    const float* __restrict__ wq, const float* __restrict__ wk,
    const float* __restrict__ wv, __hip_bfloat16* __restrict__ dst)
{
  const int WMAT = D_MODEL * D_MODEL;
  long long i = (long long)(blockIdx.x * 256 + threadIdx.x) * 8;
  long long l = i / (3LL * WMAT);
  long long rem = i - l * 3LL * WMAT;
  int which = (int)(rem / WMAT);
  long long off = rem - (long long)which * WMAT;
  const float* src = (which == 0 ? wq : which == 1 ? wk : wv) + l * WMAT + off;
  float4 a = *(const float4*)src;
  float4 b = *(const float4*)(src + 4);
  struct bf8 { __hip_bfloat16 h[8]; } r;
  r.h[0] = __float2bfloat16(a.x); r.h[1] = __float2bfloat16(a.y);
  r.h[2] = __float2bfloat16(a.z); r.h[3] = __float2bfloat16(a.w);
  r.h[4] = __float2bfloat16(b.x); r.h[5] = __float2bfloat16(b.y);
  r.h[6] = __float2bfloat16(b.z); r.h[7] = __float2bfloat16(b.w);
  *(bf8*)(dst + i) = r;
}

// convert wo|fc1|fc2 (all layers) into contiguous wob|fc1b|fc2b in one launch
__global__ __launch_bounds__(256) void convert3_kernel(
    const float* __restrict__ wo, const float* __restrict__ fc1,
    const float* __restrict__ fc2, __hip_bfloat16* __restrict__ dst)
{
  const long long WM4 = 4LL * D_MODEL * D_MODEL;   // 2,359,296
  const long long FM4 = 4LL * D_FF * D_MODEL;      // 9,437,184
  long long i = (long long)(blockIdx.x * 256 + threadIdx.x) * 8;
  const float* src;
  if (i < WM4)            src = wo  + i;
  else if (i < WM4 + FM4) src = fc1 + (i - WM4);
  else                    src = fc2 + (i - WM4 - FM4);
  float4 a = *(const float4*)src;
  float4 b = *(const float4*)(src + 4);
  struct bf8 { __hip_bfloat16 h[8]; } r;
  r.h[0] = __float2bfloat16(a.x); r.h[1] = __float2bfloat16(a.y);
  r.h[2] = __float2bfloat16(a.z); r.h[3] = __float2bfloat16(a.w);
  r.h[4] = __float2bfloat16(b.x); r.h[5] = __float2bfloat16(b.y);
  r.h[6] = __float2bfloat16(b.z); r.h[7] = __float2bfloat16(b.w);
  *(bf8*)(dst + i) = r;
}

// ---------- embedding transpose: emb [768][32000] f32 -> embT [32000][768] bf16 ----------
__global__ __launch_bounds__(256) void transpose_emb_kernel(
    const float* __restrict__ emb, __hip_bfloat16* __restrict__ embT)
{
  __shared__ float tile[64][65];
  const int vb = blockIdx.x * 64;   // vocab block
  const int db = blockIdx.y * 64;   // d block
  const int tid = threadIdx.x;
  {
    int r = tid >> 4, c = (tid & 15) * 4;
#pragma unroll
    for (int p = 0; p < 4; ++p) {
      float4 v = *(const float4*)(emb + (size_t)(db + r + p * 16) * VOCAB + vb + c);
      tile[c + 0][r + p * 16] = v.x;
      tile[c + 1][r + p * 16] = v.y;
      tile[c + 2][r + p * 16] = v.z;
      tile[c + 3][r + p * 16] = v.w;
    }
  }
  __syncthreads();
  {
    int v = tid >> 2, d0 = (tid & 3) * 16;
    unsigned short* op = (unsigned short*)embT + (size_t)(vb + v) * D_MODEL + db + d0;
    u16x8 o0, o1;
#pragma unroll
    for (int j = 0; j < 8; ++j) {
      o0[j] = f2bf(tile[v][d0 + j]);
      o1[j] = f2bf(tile[v][d0 + 8 + j]);
    }
    *(u16x8*)op = o0;
    *(u16x8*)(op + 8) = o1;
  }
}

// ---------- embedding gather (coalesced) + positional encoding ----------
__global__ __launch_bounds__(256) void embed_kernel(
    const int* __restrict__ tokens, const __hip_bfloat16* __restrict__ embT,
    float* __restrict__ x)
{
  int bs = blockIdx.x;
  int s = bs & (SEQ - 1);
  int tok = tokens[bs];
  const unsigned short* ep = (const unsigned short*)embT + (size_t)tok * D_MODEL;
  for (int d = threadIdx.x; d < D_MODEL; d += 256) {
    float ev = bf2f(ep[d]);
    int dpair = d & ~1;
    float expo = (float)dpair * (1.0f / (float)D_MODEL);
    float ang = (float)s / powf(10000.0f, expo);
    float pe = (d & 1) ? cosf(ang) : sinf(ang);
    x[(size_t)bs * D_MODEL + d] = ev + pe;
  }
}

// ---------- layer norm (fp32 in, bf16 out) ----------
__global__ __launch_bounds__(256) void ln_kernel(
    const float* __restrict__ in, __hip_bfloat16* __restrict__ out,
    const float* __restrict__ g, const float* __restrict__ bb)
{
  __shared__ float sbuf[8];
  size_t row = blockIdx.x;
  const float* rp = in + row * D_MODEL;
  int t = threadIdx.x;
  float x0 = rp[t], x1 = rp[t + 256], x2 = rp[t + 512];
  float mean = block_reduce_sum(x0 + x1 + x2, sbuf) * (1.0f / (float)D_MODEL);
  float d0 = x0 - mean, d1 = x1 - mean, d2 = x2 - mean;
  float var = block_reduce_sum(d0*d0 + d1*d1 + d2*d2, sbuf) * (1.0f / (float)D_MODEL);
  float rstd = rsqrtf(var + LN_EPS);
  __hip_bfloat16* op = out + row * D_MODEL;
  op[t]       = __float2bfloat16(g[t]       * (d0 * rstd) + bb[t]);
  op[t + 256] = __float2bfloat16(g[t + 256] * (d1 * rstd) + bb[t + 256]);
  op[t + 512] = __float2bfloat16(g[t + 512] * (d2 * rstd) + bb[t + 512]);
}

// final LN on x[b, predict_idx, :] (fp32 out)
__global__ __launch_bounds__(256) void final_ln_kernel(
    const float* __restrict__ x, const int* __restrict__ pidx,
    const float* __restrict__ g, const float* __restrict__ bb,
    float* __restrict__ out)
{
  __shared__ float sbuf[8];
  int p = pidx[0];
  const float* rp = x + ((size_t)blockIdx.x * SEQ + p) * D_MODEL;
  int t = threadIdx.x;
  float x0 = rp[t], x1 = rp[t + 256], x2 = rp[t + 512];
  float mean = block_reduce_sum(x0 + x1 + x2, sbuf) * (1.0f / (float)D_MODEL);
  float d0 = x0 - mean, d1 = x1 - mean, d2 = x2 - mean;
  float var = block_reduce_sum(d0*d0 + d1*d1 + d2*d2, sbuf) * (1.0f / (float)D_MODEL);
  float rstd = rsqrtf(var + LN_EPS);
  float* op = out + (size_t)blockIdx.x * D_MODEL;
  op[t]       = g[t]       * (d0 * rstd) + bb[t];
  op[t + 256] = g[t + 256] * (d1 * rstd) + bb[t + 256];
  op[t + 512] = g[t + 512] * (d2 * rstd) + bb[t + 512];
}

// XCD-chunked bijective block swizzle (nwg % 8 == 0 for all our grids)
__device__ __forceinline__ int2 xcd_tile(int gx, int gy) {
  int flat = blockIdx.y * gx + blockIdx.x;
  int cpx = (gx * gy) >> 3;
  int logical = (flat & 7) * cpx + (flat >> 3);
  return make_int2(logical % gx, logical / gx);   // (col, row)
}

#define WAITV4() asm volatile("s_waitcnt vmcnt(4)" ::: "memory")
#define WAITV0() asm volatile("s_waitcnt vmcnt(0)" ::: "memory")
#define MEMFENCE() asm volatile("" ::: "memory")

// ---------- bf16 MFMA NT GEMM, ring-3 counted-vmcnt pipeline ----------
// 128x128 tile, BK=32, 3 LDS buffers, depth-2 prefetch (proven round 6).
// Used for large-grid GEMMs only (QKV: 576 blocks, fc1: 768 blocks).
__global__ __launch_bounds__(256) void gemm_bf16_kernel(
    const __hip_bfloat16* __restrict__ A, const __hip_bfloat16* __restrict__ W,
    void* __restrict__ Cv, const float* __restrict__ resid,
    int N, int K, int mode)
{
  __shared__ __align__(16) unsigned short As[3][128 * 32];   // 24 KB
  __shared__ __align__(16) unsigned short Bs[3][128 * 32];   // 24 KB
  const unsigned short* Au = (const unsigned short*)A;
  const unsigned short* Wu = (const unsigned short*)W;
  const int tid = threadIdx.x;
  const int wv = tid >> 6, ln = tid & 63;
  const int l15 = ln & 15, l4 = ln >> 4;
  int2 tc = xcd_tile(N >> 7, gridDim.y);
  const int bm = tc.y * 128, bn = tc.x * 128;
  const int wr = wv >> 1, wc = wv & 1;

  const int lrow = wv * 16 + (ln >> 2);
  const int schunk = (ln & 3) ^ ((ln >> 3) & 3);
  const size_t gA0 = (size_t)(bm + lrow) * K + schunk * 8;
  const size_t gA1 = (size_t)(bm + 64 + lrow) * K + schunk * 8;
  const size_t gB0 = (size_t)(bn + lrow) * K + schunk * 8;
  const size_t gB1 = (size_t)(bn + 64 + lrow) * K + schunk * 8;
  const int ldsb = wv * 512;

#define STAGE128(buf, k0)                                                          \
  {                                                                                \
    __builtin_amdgcn_global_load_lds((g_u32*)(Au + gA0 + (k0)), (l_u32*)(As[buf] + ldsb), 16, 0, 0);        \
    __builtin_amdgcn_global_load_lds((g_u32*)(Au + gA1 + (k0)), (l_u32*)(As[buf] + 2048 + ldsb), 16, 0, 0); \
    __builtin_amdgcn_global_load_lds((g_u32*)(Wu + gB0 + (k0)), (l_u32*)(Bs[buf] + ldsb), 16, 0, 0);        \
    __builtin_amdgcn_global_load_lds((g_u32*)(Wu + gB1 + (k0)), (l_u32*)(Bs[buf] + 2048 + ldsb), 16, 0, 0); \
  }

  const int rslot = (l4 ^ ((l15 >> 1) & 3)) * 8;

#define COMPUTE128(buf)                                                            \
  {                                                                                \
    bf16x8 af[4], bfr[4];                                                          \
    _Pragma("unroll")                                                              \
    for (int m = 0; m < 4; ++m)                                                    \
      af[m] = *(const bf16x8*)(As[buf] + (wr * 64 + m * 16 + l15) * 32 + rslot);   \
    _Pragma("unroll")                                                              \
    for (int n = 0; n < 4; ++n)                                                    \
      bfr[n] = *(const bf16x8*)(Bs[buf] + (wc * 64 + n * 16 + l15) * 32 + rslot);  \
    __builtin_amdgcn_s_setprio(1);                                                 \
    _Pragma("unroll")                                                              \
    for (int m = 0; m < 4; ++m)                                                    \
      _Pragma("unroll")                                                            \
      for (int n = 0; n < 4; ++n)                                                  \
        acc[m][n] = __builtin_amdgcn_mfma_f32_16x16x32_bf16(af[m], bfr[n], acc[m][n], 0, 0, 0); \
    __builtin_amdgcn_s_setprio(0);                                                 \
  }

  f32x4 acc[4][4];
#pragma unroll
  for (int m = 0; m < 4; ++m)
#pragma unroll
    for (int n = 0; n < 4; ++n) acc[m][n] = (f32x4){0.f, 0.f, 0.f, 0.f};

  const int NT = K >> 5;
  STAGE128(0, 0);
  STAGE128(1, 32);
  int cur = 0;
  for (int t = 0; t < NT - 1; ++t) {
    WAITV4();
    __builtin_amdgcn_s_barrier();
    MEMFENCE();
    if (t + 2 < NT) {
      int nxt = cur + 2; if (nxt >= 3) nxt -= 3;
      STAGE128(nxt, (t + 2) << 5);
    }
    COMPUTE128(cur);
    cur = (cur == 2) ? 0 : cur + 1;
  }
  WAITV0();
  __builtin_amdgcn_s_barrier();
  MEMFENCE();
  COMPUTE128(cur);

  float* Cf = (float*)Cv;
  __hip_bfloat16* Cb = (__hip_bfloat16*)Cv;
#pragma unroll
  for (int m = 0; m < 4; ++m) {
#pragma unroll
    for (int n = 0; n < 4; ++n) {
#pragma unroll
      for (int r = 0; r < 4; ++r) {
        int row = bm + wr * 64 + m * 16 + l4 * 4 + r;
        int col = bn + wc * 64 + n * 16 + l15;
        size_t off = (size_t)row * N + col;
        float v = acc[m][n][r];
        if (mode == 0)      Cf[off] = v;
        else if (mode == 1) Cf[off] = v + resid[off];
        else if (mode == 2) Cb[off] = __float2bfloat16(v);
        else                Cb[off] = __float2bfloat16(gelu_f(v));
      }
    }
  }
#undef STAGE128
#undef COMPUTE128
}

// ---------- 64x64-tile variant (N=768 GEMMs: wo, fc2) ----------
// BK=64 staging geometry + ring-3 counted-vmcnt (round-8 proven: 768 blocks,
// 3/CU, fc2 ~40us). 48 KB LDS.
__global__ __launch_bounds__(256) void gemm64_bf16_kernel(
    const __hip_bfloat16* __restrict__ A, const __hip_bfloat16* __restrict__ W,
    void* __restrict__ Cv, const float* __restrict__ resid,
    int N, int K, int mode)
{
  __shared__ __align__(16) unsigned short As[3][64 * 64];   // 24 KB
  __shared__ __align__(16) unsigned short Bs[3][64 * 64];   // 24 KB
  const unsigned short* Au = (const unsigned short*)A;
  const unsigned short* Wu = (const unsigned short*)W;
  const int tid = threadIdx.x;
  const int wv = tid >> 6, ln = tid & 63;
  const int l15 = ln & 15, l4 = ln >> 4;
  int2 tc = xcd_tile(N >> 6, gridDim.y);
  const int bm = tc.y * 64, bn = tc.x * 64;
  const int wr = wv >> 1, wc = wv & 1;

  const int srow = tid >> 3;                       // 0..31
  const int schunk = (tid & 7) ^ ((tid >> 3) & 7);
  const size_t gA0 = (size_t)(bm + srow) * K + schunk * 8;
  const size_t gA1 = (size_t)(bm + 32 + srow) * K + schunk * 8;
  const size_t gB0 = (size_t)(bn + srow) * K + schunk * 8;
  const size_t gB1 = (size_t)(bn + 32 + srow) * K + schunk * 8;
  const int ldsb = wv * 512;

#define STAGE64(buf, k0)                                                           \
  {                                                                                \
    __builtin_amdgcn_global_load_lds((g_u32*)(Au + gA0 + (k0)), (l_u32*)(As[buf] + ldsb), 16, 0, 0);        \
    __builtin_amdgcn_global_load_lds((g_u32*)(Au + gA1 + (k0)), (l_u32*)(As[buf] + 2048 + ldsb), 16, 0, 0); \
    __builtin_amdgcn_global_load_lds((g_u32*)(Wu + gB0 + (k0)), (l_u32*)(Bs[buf] + ldsb), 16, 0, 0);        \
    __builtin_amdgcn_global_load_lds((g_u32*)(Wu + gB1 + (k0)), (l_u32*)(Bs[buf] + 2048 + ldsb), 16, 0, 0); \
  }

#define COMPUTE64(buf)                                                             \
  {                                                                                \
    bf16x8 af[2][2], bfr[2][2];                                                    \
    _Pragma("unroll")                                                              \
    for (int ks = 0; ks < 2; ++ks) {                                               \
      _Pragma("unroll")                                                            \
      for (int m = 0; m < 2; ++m)                                                  \
        af[ks][m] = *(const bf16x8*)(As[buf] + (wr * 32 + m * 16 + l15) * 64 +     \
                                     (((ks * 4 + l4) ^ (l15 & 7)) << 3));          \
      _Pragma("unroll")                                                            \
      for (int n = 0; n < 2; ++n)                                                  \
        bfr[ks][n] = *(const bf16x8*)(Bs[buf] + (wc * 32 + n * 16 + l15) * 64 +    \
                                      (((ks * 4 + l4) ^ (l15 & 7)) << 3));         \
    }                                                                              \
    __builtin_amdgcn_s_setprio(1);                                                 \
    _Pragma("unroll")                                                              \
    for (int ks = 0; ks < 2; ++ks)                                                 \
      _Pragma("unroll")                                                            \
      for (int m = 0; m < 2; ++m)                                                  \
        _Pragma("unroll")                                                          \
        for (int n = 0; n < 2; ++n)                                                \
          acc[m][n] = __builtin_amdgcn_mfma_f32_16x16x32_bf16(af[ks][m], bfr[ks][n], acc[m][n], 0, 0, 0); \
    __builtin_amdgcn_s_setprio(0);                                                 \
  }

  f32x4 acc[2][2];
#pragma unroll
  for (int m = 0; m < 2; ++m)
#pragma unroll
    for (int n = 0; n < 2; ++n) acc[m][n] = (f32x4){0.f, 0.f, 0.f, 0.f};

  const int NT = K >> 6;            // wo: 12, fc2: 48
  STAGE64(0, 0);
  STAGE64(1, 64);
  int cur = 0;
  for (int t = 0; t < NT - 1; ++t) {
    WAITV4();
    __builtin_amdgcn_s_barrier();
    MEMFENCE();
    if (t + 2 < NT) {
      int nxt = cur + 2; if (nxt >= 3) nxt -= 3;
      STAGE64(nxt, (t + 2) << 6);
    }
    COMPUTE64(cur);
    cur = (cur == 2) ? 0 : cur + 1;
  }
  WAITV0();
  __builtin_amdgcn_s_barrier();
  MEMFENCE();
  COMPUTE64(cur);

  float* Cf = (float*)Cv;
  __hip_bfloat16* Cb = (__hip_bfloat16*)Cv;
#pragma unroll
  for (int m = 0; m < 2; ++m) {
#pragma unroll
    for (int n = 0; n < 2; ++n) {
#pragma unroll
      for (int r = 0; r < 4; ++r) {
        int row = bm + wr * 32 + m * 16 + l4 * 4 + r;
        int col = bn + wc * 32 + n * 16 + l15;
        size_t off = (size_t)row * N + col;
        float v = acc[m][n][r];
        if (mode == 0)      Cf[off] = v;
        else if (mode == 1) Cf[off] = v + resid[off];
        else if (mode == 2) Cb[off] = __float2bfloat16(v);
        else                Cb[off] = __float2bfloat16(gelu_f(v));
      }
    }
  }
#undef STAGE64
#undef COMPUTE64
}

// ---------- MFMA flash attention v2 (round 7) + T5 setprio ----------
__global__ __launch_bounds__(128) void flash_attn_kernel(
    const __hip_bfloat16* __restrict__ qkv_, __hip_bfloat16* __restrict__ attn_)
{
  const unsigned short* qkv = (const unsigned short*)qkv_;
  unsigned short* attn = (unsigned short*)attn_;
  const int px = blockIdx.x;        // pair index 0..15
  const int h  = blockIdx.y;
  const int b  = blockIdx.z;
  const int tid = threadIdx.x;      // 0..127
  const int wq = tid >> 6, ln = tid & 63;
  const int l15 = ln & 15, l4 = ln >> 4;

  __shared__ unsigned short Ks[2][64 * 64];   // 16 KB, [t][d] XOR-swizzled
  __shared__ unsigned short Vt[2][64 * 64];   // 16 KB, [e][t] XOR-swizzled
  __shared__ unsigned short Pw[2][16 * 64];   // 4 KB, per-wave P [q][t]

  const int krow = tid >> 3;
  const int kchunk = (tid & 7) ^ ((tid >> 3) & 7);
  const int kldsbase = (tid & 64) * 8;   // wave-uniform base (elems)

  const int vc = tid & 7;          // e-chunk
  const int vp = tid >> 3;         // 0..15
  const int vtr = (2 * vp) & 7;    // even within-chunk t offset
  const int vtb0 = vp >> 2;        // t-chunk of rows 2vp..

  u16x8 v0, v1, v2, v3;            // V prefetch registers

#define STAGE_K(buf, t0)                                                           \
  {                                                                                \
    _Pragma("unroll")                                                              \
    for (int j = 0; j < 4; ++j) {                                                  \
      const unsigned short* gk = qkv +                                             \
          (size_t)(b * SEQ + (t0) + j * 16 + krow) * 2304 + 768 + h * 64 + kchunk * 8; \
      __builtin_amdgcn_global_load_lds((g_u32*)gk,                                 \
          (l_u32*)(Ks[buf] + j * 1024 + kldsbase), 16, 0, 0);                      \
    }                                                                              \
  }

#define LOAD_V(t0)                                                                 \
  {                                                                                \
    const unsigned short* gv = qkv +                                               \
        (size_t)(b * SEQ + (t0) + 2 * vp) * 2304 + 1536 + h * 64 + vc * 8;         \
    v0 = *(const u16x8*)gv;                                                        \
    v1 = *(const u16x8*)(gv + 2304);                                               \
    v2 = *(const u16x8*)(gv + 32 * 2304);                                          \
    v3 = *(const u16x8*)(gv + 33 * 2304);                                          \
  }

#define WRITE_VT(buf)                                                              \
  {                                                                                \
    _Pragma("unroll")                                                              \
    for (int j = 0; j < 8; ++j) {                                                  \
      int e = vc * 8 + j;                                                          \
      unsigned int w01 = (unsigned int)(unsigned short)v0[j] |                     \
                         ((unsigned int)(unsigned short)v1[j] << 16);              \
      unsigned int w23 = (unsigned int)(unsigned short)v2[j] |                     \
                         ((unsigned int)(unsigned short)v3[j] << 16);              \
      *(unsigned int*)(Vt[buf] + e * 64 + ((vtb0 ^ (e & 7)) << 3) + vtr) = w01;    \
      *(unsigned int*)(Vt[buf] + e * 64 + (((vtb0 + 4) ^ (e & 7)) << 3) + vtr) = w23; \
    }                                                                              \
  }

  for (int pass = 0; pass < 2; ++pass) {
    const int qi = (pass == 0) ? px : 31 - px;
    const int s0 = qi * 32;
    const int ntiles = (qi >> 1) + 1;
    const int qg = s0 + wq * 16 + l15;   // this lane's q row

    bf16x8 qf[2];
    {
      const size_t qbase = (size_t)(b * SEQ + qg) * 2304 + h * 64;
#pragma unroll
      for (int ks = 0; ks < 2; ++ks) {
        u16x8 raw = *(const u16x8*)(qkv + qbase + ks * 32 + l4 * 8);
        bf16x8 q;
#pragma unroll
        for (int j = 0; j < 8; ++j) q[j] = (short)f2bf(bf2f(raw[j]) * 0.125f);
        qf[ks] = q;
      }
    }

    float mrow = -1e30f, lrow = 0.f;
    f32x4 o[4];
#pragma unroll
    for (int n = 0; n < 4; ++n) o[n] = (f32x4){0.f, 0.f, 0.f, 0.f};

    STAGE_K(0, 0);
    LOAD_V(0);
    WAITV0();
    WRITE_VT(0);
    __syncthreads();

    for (int t = 0; t < ntiles; ++t) {
      const int cur = t & 1;
      const bool pfn = (t + 1 < ntiles);
      if (pfn) { STAGE_K(cur ^ 1, (t + 1) * 64); LOAD_V((t + 1) * 64); }

      f32x4 sf[4];
#pragma unroll
      for (int n = 0; n < 4; ++n) sf[n] = (f32x4){0.f, 0.f, 0.f, 0.f};
      __builtin_amdgcn_s_setprio(1);
#pragma unroll
      for (int ks = 0; ks < 2; ++ks) {
#pragma unroll
        for (int n = 0; n < 4; ++n) {
          int tr = n * 16 + l15;
          bf16x8 kf = *(const bf16x8*)(Ks[cur] + tr * 64 + (((ks * 4 + l4) ^ (tr & 7)) << 3));
          sf[n] = __builtin_amdgcn_mfma_f32_16x16x32_bf16(kf, qf[ks], sf[n], 0, 0, 0);
        }
      }
      __builtin_amdgcn_s_setprio(0);

      if (t == ntiles - 1) {
#pragma unroll
        for (int n = 0; n < 4; ++n) {
#pragma unroll
          for (int r = 0; r < 4; ++r) {
            int tg = t * 64 + n * 16 + l4 * 4 + r;
            if (tg > qg) sf[n][r] = NEGV;
          }
        }
      }

      float mx = sf[0][0];
#pragma unroll
      for (int n = 0; n < 4; ++n)
#pragma unroll
        for (int r = 0; r < 4; ++r) mx = fmaxf(mx, sf[n][r]);
      mx = fmaxf(mx, __shfl_xor(mx, 16));
      mx = fmaxf(mx, __shfl_xor(mx, 32));
      float mnew = fmaxf(mrow, mx);
      float alpha = __expf(mrow - mnew);
      float pb[4][4];
      float sum = 0.f;
#pragma unroll
      for (int n = 0; n < 4; ++n)
#pragma unroll
        for (int r = 0; r < 4; ++r) {
          float p = __expf(sf[n][r] - mnew);
          pb[n][r] = p;
          sum += p;
        }
      sum += __shfl_xor(sum, 16);
      sum += __shfl_xor(sum, 32);
      lrow = lrow * alpha + sum;
      mrow = mnew;

      float ar[4];
#pragma unroll
      for (int r = 0; r < 4; ++r)
        ar[r] = __shfl(alpha, (ln & 48) | (l4 * 4 + r));
#pragma unroll
      for (int n = 0; n < 4; ++n)
#pragma unroll
        for (int r = 0; r < 4; ++r) o[n][r] *= ar[r];

      unsigned short* Pme = Pw[wq];
#pragma unroll
      for (int n = 0; n < 4; ++n) {
        int tb = 2 * n + (l4 >> 1);
        u16x4 w;
        w[0] = f2bf(pb[n][0]); w[1] = f2bf(pb[n][1]);
        w[2] = f2bf(pb[n][2]); w[3] = f2bf(pb[n][3]);
        *(u16x4*)(Pme + l15 * 64 + ((tb ^ (l15 & 7)) << 3) + (l4 & 1) * 4) = w;
      }

      __builtin_amdgcn_s_setprio(1);
#pragma unroll
      for (int ks = 0; ks < 2; ++ks) {
        bf16x8 pf = *(const bf16x8*)(Pme + l15 * 64 + (((ks * 4 + l4) ^ (l15 & 7)) << 3));
#pragma unroll
        for (int n = 0; n < 4; ++n) {
          int e = n * 16 + l15;
          bf16x8 vf = *(const bf16x8*)(Vt[cur] + e * 64 + (((ks * 4 + l4) ^ (e & 7)) << 3));
          o[n] = __builtin_amdgcn_mfma_f32_16x16x32_bf16(pf, vf, o[n], 0, 0, 0);
        }
      }
      __builtin_amdgcn_s_setprio(0);

      if (pfn) { WAITV0(); WRITE_VT(cur ^ 1); }
      __syncthreads();
    }

    float lr[4];
#pragma unroll
    for (int r = 0; r < 4; ++r)
      lr[r] = __shfl(lrow, (ln & 48) | (l4 * 4 + r));
#pragma unroll
    for (int r = 0; r < 4; ++r) {
      float inv = 1.0f / lr[r];
      size_t base = (size_t)(b * SEQ + s0 + wq * 16 + l4 * 4 + r) * D_MODEL + h * 64;
#pragma unroll
      for (int n = 0; n < 4; ++n)
        attn[base + n * 16 + l15] = f2bf(o[n][r] * inv);
    }
  }
#undef STAGE_K
#undef LOAD_V
#undef WRITE_VT
}

// ---------- logits: out[b,v] = dot(normed[b,:], unembed[v,:]) ----------
__global__ __launch_bounds__(256) void logits_kernel(
    const float* __restrict__ normed, const float* __restrict__ unemb,
    float* __restrict__ out)
{
  __shared__ __align__(16) float ns[BATCH][D_MODEL];
  for (int d = threadIdx.x; d < BATCH * D_MODEL; d += 256)
    ((float*)ns)[d] = normed[d];
  __syncthreads();
  int g = threadIdx.x >> 4, li = threadIdx.x & 15;
  int v = blockIdx.x * 16 + g;
  const float* up = unemb + (size_t)v * D_MODEL;
  float s0 = 0.f, s1 = 0.f, s2 = 0.f, s3 = 0.f;
#pragma unroll
  for (int it = 0; it < D_MODEL / 64; ++it) {
    int e = it * 64 + li * 4;
    float4 u = *(const float4*)(up + e);
    float4 n0 = *(const float4*)&ns[0][e];
    float4 n1 = *(const float4*)&ns[1][e];
    float4 n2 = *(const float4*)&ns[2][e];
    float4 n3 = *(const float4*)&ns[3][e];
    s0 += u.x*n0.x + u.y*n0.y + u.z*n0.z + u.w*n0.w;
    s1 += u.x*n1.x + u.y*n1.y + u.z*n1.z + u.w*n1.w;
    s2 += u.x*n2.x + u.y*n2.y + u.z*n2.z + u.w*n2.w;
    s3 += u.x*n3.x + u.y*n3.y + u.z*n3.z + u.w*n3.w;
  }
#pragma unroll
  for (int msk = 1; msk < 16; msk <<= 1) {
    s0 += __shfl_xor(s0, msk, 64); s1 += __shfl_xor(s1, msk, 64);
    s2 += __shfl_xor(s2, msk, 64); s3 += __shfl_xor(s3, msk, 64);
  }
  if (li == 0) {
    out[(size_t)0 * VOCAB + v] = s0;
    out[(size_t)1 * VOCAB + v] = s1;
    out[(size_t)2 * VOCAB + v] = s2;
    out[(size_t)3 * VOCAB + v] = s3;
  }
}

// ---------- launcher ----------
extern "C" void kernel_launch(void* const* d_in, const int* in_sizes, int n_in,
                              void* d_out, int out_size, void* d_ws, size_t ws_size,
                              hipStream_t stream) {
  const int*   tokens = (const int*)d_in[0];
  const int*   pidx   = (const int*)d_in[1];
  const float* emb    = (const float*)d_in[2];
  const float* ln1_g  = (const float*)d_in[3];
  const float* ln1_b  = (const float*)d_in[4];
  const float* wq     = (const float*)d_in[5];
  const float* wk     = (const float*)d_in[6];
  const float* wv     = (const float*)d_in[7];
  const float* wo     = (const float*)d_in[8];
  const float* ln2_g  = (const float*)d_in[9];
  const float* ln2_b  = (const float*)d_in[10];
  const float* fc1    = (const float*)d_in[11];
  const float* fc2    = (const float*)d_in[12];
  const float* lnf_g  = (const float*)d_in[13];
  const float* lnf_b  = (const float*)d_in[14];
  const float* unemb  = (const float*)d_in[15];
  float* out = (float*)d_out;

  char* wp = (char*)d_ws;
  const size_t NX = (size_t)NROWS * D_MODEL;        // 3,145,728
  float* x = (float*)wp;                  wp += NX * 4;
  float* normed = (float*)wp;             wp += BATCH * D_MODEL * 4;
  __hip_bfloat16* h    = (__hip_bfloat16*)wp; wp += NX * 2;
  __hip_bfloat16* attn = (__hip_bfloat16*)wp; wp += NX * 2;
  __hip_bfloat16* qkvb = (__hip_bfloat16*)wp; wp += (size_t)NROWS * 2304 * 2;
  __hip_bfloat16* ffn  = (__hip_bfloat16*)wp; wp += (size_t)NROWS * D_FF * 2;
  __hip_bfloat16* wqkvb = (__hip_bfloat16*)wp; wp += (size_t)N_LAYERS * 2304 * D_MODEL * 2;
  __hip_bfloat16* wob   = (__hip_bfloat16*)wp; wp += (size_t)N_LAYERS * D_MODEL * D_MODEL * 2;
  __hip_bfloat16* fc1b  = (__hip_bfloat16*)wp; wp += (size_t)N_LAYERS * D_FF * D_MODEL * 2;
  __hip_bfloat16* fc2b  = (__hip_bfloat16*)wp; wp += (size_t)N_LAYERS * D_MODEL * D_FF * 2;

  // embT [VOCAB][D_MODEL] bf16 (49.2 MB) aliased onto attn..ffn scratch
  __hip_bfloat16* embT = attn;

  const int WMAT = D_MODEL * D_MODEL;     // 589824
  const int FMAT = D_FF * D_MODEL;        // 2359296

  transpose_emb_kernel<<<dim3(VOCAB / 64, D_MODEL / 64), 256, 0, stream>>>(emb, embT);
  embed_kernel<<<NROWS, 256, 0, stream>>>(tokens, embT, x);

  qkv_pack_kernel<<<N_LAYERS * 3 * WMAT / 2048, 256, 0, stream>>>(wq, wk, wv, wqkvb);
  // wob|fc1b|fc2b are contiguous: one fused convert launch
  convert3_kernel<<<(N_LAYERS * (WMAT + 2 * FMAT)) / 2048, 256, 0, stream>>>(wo, fc1, fc2, wob);

  for (int l = 0; l < N_LAYERS; ++l) {
    const size_t qofs = (size_t)l * 3 * WMAT;
    const size_t wofs = (size_t)l * WMAT;
    const size_t fofs = (size_t)l * FMAT;

    ln_kernel<<<NROWS, 256, 0, stream>>>(x, h, ln1_g + l * D_MODEL, ln1_b + l * D_MODEL);

    // fused QKV: [4096 x 2304] bf16 out (576 blocks)
    gemm_bf16_kernel<<<dim3(2304 / 128, NROWS / 128), 256, 0, stream>>>(
        h, wqkvb + qofs, qkvb, nullptr, 2304, D_MODEL, 2);

    flash_attn_kernel<<<dim3(16, N_HEADS, BATCH), 128, 0, stream>>>(qkvb, attn);

    // x += attn @ wo^T  (64-tile: 768 blocks, 3/CU)
    gemm64_bf16_kernel<<<dim3(D_MODEL / 64, NROWS / 64), 256, 0, stream>>>(
        attn, wob + wofs, x, x, D_MODEL, D_MODEL, 1);

    ln_kernel<<<NROWS, 256, 0, stream>>>(x, h, ln2_g + l * D_MODEL, ln2_b + l * D_MODEL);

    // ffn = gelu(h @ fc1^T) (bf16, 768 blocks)
    gemm_bf16_kernel<<<dim3(D_FF / 128, NROWS / 128), 256, 0, stream>>>(
        h, fc1b + fofs, ffn, nullptr, D_FF, D_MODEL, 3);

    // x += ffn @ fc2^T  (64-tile: 768 blocks, 3/CU)
    gemm64_bf16_kernel<<<dim3(D_MODEL / 64, NROWS / 64), 256, 0, stream>>>(
        ffn, fc2b + fofs, x, x, D_MODEL, D_FF, 1);
  }

  final_ln_kernel<<<BATCH, 256, 0, stream>>>(x, pidx, lnf_g, lnf_b, normed);
  logits_kernel<<<VOCAB / 16, 256, 0, stream>>>(normed, unemb, out);
}